// Round 1
// baseline (423.978 us; speedup 1.0000x reference)
//
#include <hip/hip_runtime.h>
#include <hip/hip_bf16.h>

// Problem dims (fixed by reference)
#define B_SZ 4096
#define F_SZ 1024
#define P_SZ 64
#define H1D  256
#define H2D  128

typedef __attribute__((ext_vector_type(8))) short  short8;   // 8 bf16 (4 VGPR) MFMA operand
typedef __attribute__((ext_vector_type(4))) float  floatx4;  // MFMA accumulator
typedef __attribute__((ext_vector_type(2))) float  float2v;
typedef __attribute__((ext_vector_type(4))) float  float4v;

__device__ __forceinline__ short bfbits(float f) {
  __bf16 h = (__bf16)f;            // RNE, compiler emits v_cvt_pk_bf16_f32
  return __builtin_bit_cast(short, h);
}

// Fused: h1 = relu(feat @ W1[p] + b1[p]); h2 = relu(h1 @ W2[p] + b2[p]);
// out[b][p] = sigmoid(h2 @ W3[p] + b3[p])
// Block: one (p, 128-row m-tile). 512 threads = 8 waves (2 M x 4 N), wave tile 64x64.
// LDS frag-major layout: buf[frag_idx][lane][8 bf16] -> lane-linear ds_read_b128/ds_write_b128.
__global__ __launch_bounds__(512, 2)
void fused_mlp_kernel(const float* __restrict__ feat,
                      const float* __restrict__ W1,
                      const float* __restrict__ b1,
                      const float* __restrict__ W2,
                      const float* __restrict__ b2,
                      const float* __restrict__ W3,
                      const float* __restrict__ b3,
                      float* __restrict__ out) {
  __shared__ __align__(16) char sm[49152];
  // Phase 1: A dbuf  [0, 16384)   : 2 x 8192  (128m x 32k bf16, frag-major)
  //          B dbuf  [16384,49152): 2 x 16384 (32k x 256n bf16, frag-major)
  // Phase 2 (overlay): bufH [0,16384), bufW2T [16384,32768), partial f32 [32768,34816)

  const int tid  = threadIdx.x;
  const int lane = tid & 63;
  const int wid  = tid >> 6;
  const int wm   = wid >> 2;   // 0..1 : m-half (64 rows)
  const int wn   = wid & 3;    // 0..3 : n-quarter (64 cols of H1)

  // XCD-chunked swizzle: XCD x gets contiguous logical range (8 p's) -> W1[p] stays L2-hot.
  const int bid = blockIdx.x;
  const int wg  = (bid & 7) * 256 + (bid >> 3);   // 2048 % 8 == 0 -> bijective
  const int p   = wg >> 5;                        // 32 m-tiles per p
  const int mt  = wg & 31;
  const int m0  = mt * 128;

  const float* featm = feat + (size_t)m0 * F_SZ;
  const float* W1p   = W1 + (size_t)p * F_SZ * H1D;
  const float* b1p   = b1 + p * H1D;
  const float* W2p   = W2 + (size_t)p * H1D * H2D;
  const float* b2p   = b2 + p * H2D;
  const float* W3p   = W3 + p * H2D;

  // ---- Phase 1 staging thread mapping ----
  const int a_m  = tid >> 2;     // 0..127 row
  const int a_kg = tid & 3;      // 0..3   k-subgroup of 8
  const int b_n2 = tid & 127;    // n = 2*b_n2 (+0/1)
  const int b_kq = tid >> 7;     // 0..3   k-subgroup of 8

  float a_reg[8];
  float b_reg[16];

  floatx4 acc[4][4];
  #pragma unroll
  for (int i = 0; i < 4; ++i)
    #pragma unroll
    for (int j = 0; j < 4; ++j)
      acc[i][j] = (floatx4)0.0f;

  auto stage_load = [&](int k0) {
    const float* pa = featm + a_m * F_SZ + k0 + a_kg * 8;
    *(float4v*)(&a_reg[0]) = *(const float4v*)(pa);
    *(float4v*)(&a_reg[4]) = *(const float4v*)(pa + 4);
    #pragma unroll
    for (int i = 0; i < 8; ++i) {
      const float* pb = W1p + (size_t)(k0 + b_kq * 8 + i) * H1D + b_n2 * 2;
      *(float2v*)(&b_reg[2 * i]) = *(const float2v*)(pb);
    }
  };

  auto stage_write = [&](int cur) {
    short8 av;
    #pragma unroll
    for (int i = 0; i < 8; ++i) av[i] = bfbits(a_reg[i]);
    const int aslot = (a_m >> 4) * 64 + (a_m & 15) + a_kg * 16;
    *(short8*)(sm + cur * 8192 + aslot * 16) = av;
    #pragma unroll
    for (int dn = 0; dn < 2; ++dn) {
      short8 bv;
      #pragma unroll
      for (int i = 0; i < 8; ++i) bv[i] = bfbits(b_reg[2 * i + dn]);
      const int n = b_n2 * 2 + dn;
      const int bslot = (n >> 4) * 64 + (n & 15) + b_kq * 16;
      *(short8*)(sm + 16384 + cur * 16384 + bslot * 16) = bv;
    }
  };

  auto compute = [&](int cur) {
    short8 af[4], bfr[4];
    #pragma unroll
    for (int mi = 0; mi < 4; ++mi)
      af[mi] = *(const short8*)(sm + cur * 8192 + ((wm * 4 + mi) * 64 + lane) * 16);
    #pragma unroll
    for (int ni = 0; ni < 4; ++ni)
      bfr[ni] = *(const short8*)(sm + 16384 + cur * 16384 + ((wn * 4 + ni) * 64 + lane) * 16);
    #pragma unroll
    for (int mi = 0; mi < 4; ++mi)
      #pragma unroll
      for (int ni = 0; ni < 4; ++ni)
        acc[mi][ni] = __builtin_amdgcn_mfma_f32_16x16x32_bf16(af[mi], bfr[ni], acc[mi][ni], 0, 0, 0);
  };

  // ---- Layer 1 main loop: K = 1024 in 32 steps of BK=32, double-buffered ----
  stage_load(0);
  stage_write(0);
  __syncthreads();
  int cur = 0;
  for (int t = 0; t < 32; ++t) {
    if (t + 1 < 32) stage_load((t + 1) * 32);   // issue early (latency hides under MFMA)
    compute(cur);
    if (t + 1 < 32) stage_write(cur ^ 1);
    __syncthreads();
    cur ^= 1;
  }

  // ---- Phase 2: layer 2 (K = H1 = 256, 4 chunks of 64), fused layer 3 ----
  floatx4 acc2[4][2];
  #pragma unroll
  for (int mi = 0; mi < 4; ++mi)
    #pragma unroll
    for (int qi = 0; qi < 2; ++qi)
      acc2[mi][qi] = (floatx4)0.0f;

  float b1v[4];
  #pragma unroll
  for (int ni = 0; ni < 4; ++ni)
    b1v[ni] = b1p[wn * 64 + ni * 16 + (lane & 15)];

  const int w2_q2 = tid & 63;  // q = 2*w2_q2 (+0/1)
  const int w2_kq = tid >> 6;  // 0..7  k-subgroup of 8 within chunk

  for (int kc = 0; kc < 4; ++kc) {
    const int kbase = kc * 64;
    // stage W2^T chunk (all threads): bufW[qf][ks][lane][8bf16]
    float w2reg[16];
    #pragma unroll
    for (int i = 0; i < 8; ++i) {
      const float* pw = W2p + (size_t)(kbase + w2_kq * 8 + i) * H2D + w2_q2 * 2;
      *(float2v*)(&w2reg[2 * i]) = *(const float2v*)(pw);
    }
    #pragma unroll
    for (int dq = 0; dq < 2; ++dq) {
      short8 wv;
      #pragma unroll
      for (int i = 0; i < 8; ++i) wv[i] = bfbits(w2reg[2 * i + dq]);
      const int q = w2_q2 * 2 + dq;
      const int slot = ((q >> 4) * 2 + (w2_kq >> 2)) * 64 + (w2_kq & 3) * 16 + (q & 15);
      *(short8*)(sm + 16384 + slot * 16) = wv;
    }
    // owner waves (wn == kc) scatter relu(h1 + b1) into A-frag layout: bufH[mf][ks][lane][8bf16]
    if (wn == kc) {
      #pragma unroll
      for (int mi = 0; mi < 4; ++mi) {
        #pragma unroll
        for (int ni = 0; ni < 4; ++ni) {
          const int kl = ni * 16 + (lane & 15);            // 0..63 within chunk
          const int base = (((wm * 4 + mi) * 2 + (kl >> 5)) * 64 + ((kl >> 3) & 3) * 16) * 16
                           + (kl & 7) * 2;
          #pragma unroll
          for (int r = 0; r < 4; ++r) {
            float v = fmaxf(acc[mi][ni][r] + b1v[ni], 0.0f);
            const int row = (lane >> 4) * 4 + r;           // m & 15
            *(short*)(sm + base + row * 16) = bfbits(v);
          }
        }
      }
    }
    __syncthreads();
    #pragma unroll
    for (int ks = 0; ks < 2; ++ks) {
      short8 hf[4], wf[2];
      #pragma unroll
      for (int mi = 0; mi < 4; ++mi)
        hf[mi] = *(const short8*)(sm + (((wm * 4 + mi) * 2 + ks) * 64 + lane) * 16);
      #pragma unroll
      for (int qi = 0; qi < 2; ++qi)
        wf[qi] = *(const short8*)(sm + 16384 + (((wn * 2 + qi) * 2 + ks) * 64 + lane) * 16);
      #pragma unroll
      for (int mi = 0; mi < 4; ++mi)
        #pragma unroll
        for (int qi = 0; qi < 2; ++qi)
          acc2[mi][qi] = __builtin_amdgcn_mfma_f32_16x16x32_bf16(hf[mi], wf[qi], acc2[mi][qi], 0, 0, 0);
    }
    __syncthreads();
  }

  // ---- Layer 3: logits = relu(h2+b2) . W3 + b3 ; sigmoid; store transposed ----
  float lsum[4][4];
  #pragma unroll
  for (int mi = 0; mi < 4; ++mi)
    #pragma unroll
    for (int r = 0; r < 4; ++r) lsum[mi][r] = 0.0f;

  #pragma unroll
  for (int qi = 0; qi < 2; ++qi) {
    const int q = wn * 32 + qi * 16 + (lane & 15);
    const float b2v = b2p[q];
    const float w3v = W3p[q];
    #pragma unroll
    for (int mi = 0; mi < 4; ++mi)
      #pragma unroll
      for (int r = 0; r < 4; ++r) {
        const float h = fmaxf(acc2[mi][qi][r] + b2v, 0.0f);
        lsum[mi][r] += h * w3v;
      }
  }
  // reduce across the 16 lanes (columns) of each row group
  #pragma unroll
  for (int mask = 1; mask <= 8; mask <<= 1)
    #pragma unroll
    for (int mi = 0; mi < 4; ++mi)
      #pragma unroll
      for (int r = 0; r < 4; ++r)
        lsum[mi][r] += __shfl_xor(lsum[mi][r], mask, 64);

  float* part = (float*)(sm + 32768);  // [4][128] per-wn partial row sums
  if ((lane & 15) == 0) {
    const int g = lane >> 4;
    #pragma unroll
    for (int mi = 0; mi < 4; ++mi)
      #pragma unroll
      for (int r = 0; r < 4; ++r)
        part[wn * 128 + wm * 64 + mi * 16 + g * 4 + r] = lsum[mi][r];
  }
  __syncthreads();
  if (tid < 128) {
    const float x = part[tid] + part[128 + tid] + part[256 + tid] + part[384 + tid] + b3[p];
    const float s = 1.0f / (1.0f + __expf(-x));
    out[(size_t)(m0 + tid) * P_SZ + p] = s;
  }
}

extern "C" void kernel_launch(void* const* d_in, const int* in_sizes, int n_in,
                              void* d_out, int out_size, void* d_ws, size_t ws_size,
                              hipStream_t stream) {
  (void)in_sizes; (void)n_in; (void)d_ws; (void)ws_size; (void)out_size;
  const float* feat = (const float*)d_in[0];
  const float* W1   = (const float*)d_in[1];
  const float* b1   = (const float*)d_in[2];
  const float* W2   = (const float*)d_in[3];
  const float* b2   = (const float*)d_in[4];
  const float* W3   = (const float*)d_in[5];
  const float* b3   = (const float*)d_in[6];
  float* out = (float*)d_out;

  hipLaunchKernelGGL(fused_mlp_kernel, dim3(2048), dim3(512), 0, stream,
                     feat, W1, b1, W2, b2, W3, b3, out);
}

// Round 2
// 246.605 us; speedup vs baseline: 1.7193x; 1.7193x over previous
//
#include <hip/hip_runtime.h>
#include <hip/hip_bf16.h>

// Problem dims (fixed by reference)
#define B_SZ 4096
#define F_SZ 1024
#define P_SZ 64
#define H1D  256
#define H2D  128

typedef __attribute__((ext_vector_type(8))) short  short8;   // 8 bf16 (4 VGPR) MFMA operand
typedef __attribute__((ext_vector_type(4))) float  floatx4;  // MFMA accumulator
typedef __attribute__((ext_vector_type(2))) float  float2v;
typedef __attribute__((ext_vector_type(4))) float  float4v;

typedef __attribute__((address_space(1))) const void* gas_t;
typedef __attribute__((address_space(3))) void*       las_t;

__device__ __forceinline__ short bfbits(float f) {
  __bf16 h = (__bf16)f;            // RNE, v_cvt_pk_bf16_f32
  return __builtin_bit_cast(short, h);
}

__device__ __forceinline__ void gll16(const void* g, void* l) {
  __builtin_amdgcn_global_load_lds((gas_t)g, (las_t)l, 16, 0, 0);
}

// ---------------- ws layout (bf16, fragment-major) ----------------
// A_pre  [0,        8388608): feat  -> [mt(32)][kt(32)][slot(512)][8]
//        slot = f*64 + kg*16 + row ; value = feat[mt*128+f*16+row][kt*32+kg*8+j]
// W1_pre [8388608, 41943040): W1    -> [p(64)][kt(32)][slot(1024)][8]
//        slot = nf*64 + kg*16 + nr ; value = W1[p][kt*32+kg*8+j][nf*16+nr]
// W2_pre [41943040,46137344): W2    -> [p(64)][kc(4)][slot(1024)][8]
//        slot = qf*128 + ks*64 + kgl*16 + qr ; value = W2[p][kc*64+ks*32+kgl*8+j][qf*16+qr]
#define WS_A_OFF   0
#define WS_W1_OFF  8388608UL
#define WS_W2_OFF  41943040UL
#define WS_NEEDED  46137344UL

__global__ __launch_bounds__(256) void prep_A(const float* __restrict__ feat,
                                              short8* __restrict__ outv) {
  const int c = blockIdx.x * 256 + threadIdx.x;   // 524288 chunks
  const int row = c & 15, kg = (c >> 4) & 3, f = (c >> 6) & 7, kt = (c >> 9) & 31, mt = c >> 14;
  const float* src = feat + (size_t)(mt * 128 + f * 16 + row) * F_SZ + kt * 32 + kg * 8;
  float4v v0 = *(const float4v*)src;
  float4v v1 = *(const float4v*)(src + 4);
  short8 o;
  #pragma unroll
  for (int j = 0; j < 4; ++j) { o[j] = bfbits(v0[j]); o[4 + j] = bfbits(v1[j]); }
  outv[c] = o;
}

__global__ __launch_bounds__(256) void prep_W1(const float* __restrict__ W1,
                                               short8* __restrict__ outv) {
  const int c = blockIdx.x * 256 + threadIdx.x;   // 2097152 chunks
  const int nr = c & 15, kg = (c >> 4) & 3, nf = (c >> 6) & 15, kt = (c >> 10) & 31, p = c >> 15;
  const float* src = W1 + ((size_t)p * F_SZ + kt * 32 + kg * 8) * H1D + nf * 16 + nr;
  short8 o;
  #pragma unroll
  for (int j = 0; j < 8; ++j) o[j] = bfbits(src[(size_t)j * H1D]);
  outv[c] = o;
}

__global__ __launch_bounds__(256) void prep_W2(const float* __restrict__ W2,
                                               short8* __restrict__ outv) {
  const int c = blockIdx.x * 256 + threadIdx.x;   // 262144 chunks
  const int qr = c & 15, kgl = (c >> 4) & 3, ks = (c >> 6) & 1, qf = (c >> 7) & 7,
            kc = (c >> 10) & 3, p = c >> 12;
  const float* src = W2 + ((size_t)p * H1D + kc * 64 + ks * 32 + kgl * 8) * H2D + qf * 16 + qr;
  short8 o;
  #pragma unroll
  for (int j = 0; j < 8; ++j) o[j] = bfbits(src[(size_t)j * H2D]);
  outv[c] = o;
}

// ---------------- main fused kernel (bf16 pre-converted path) ----------------
// Block: one (p, 128-row m-tile). 512 threads = 8 waves (2 M x 4 N), wave tile 64x64.
// Phase 1 LDS: A dbuf [0,16384): 2 x 8192 ; B dbuf [16384,49152): 2 x 16384
// Phase 2 overlay: bufH [0,16384) ; bufW2 [16384,32768) ; partial f32 [32768,34816)
__global__ __launch_bounds__(512, 2)
void fused_mlp_v2(const char* __restrict__ ws,
                  const float* __restrict__ b1,
                  const float* __restrict__ b2,
                  const float* __restrict__ W3,
                  const float* __restrict__ b3,
                  float* __restrict__ out) {
  __shared__ __align__(16) char sm[49152];

  const int tid  = threadIdx.x;
  const int lane = tid & 63;
  const int wid  = tid >> 6;
  const int wm   = wid >> 2;   // 0..1
  const int wn   = wid & 3;    // 0..3

  const int bid = blockIdx.x;
  const int wg  = (bid & 7) * 256 + (bid >> 3);   // XCD-chunked, bijective (2048%8==0)
  const int p   = wg >> 5;
  const int mt  = wg & 31;
  const int m0  = mt * 128;

  const char* Apre  = ws + WS_A_OFF  + (size_t)mt * 32 * 512 * 16;   // per-kt chunks of 8KB
  const char* W1pre = ws + WS_W1_OFF + (size_t)p  * 32 * 1024 * 16;  // per-kt chunks of 16KB
  const char* W2pre = ws + WS_W2_OFF + (size_t)p  *  4 * 1024 * 16;  // per-kc chunks of 16KB
  const float* b1p  = b1 + p * H1D;
  const float* b2p  = b2 + p * H2D;
  const float* W3p  = W3 + p * H2D;

  floatx4 acc[4][4];
  #pragma unroll
  for (int i = 0; i < 4; ++i)
    #pragma unroll
    for (int j = 0; j < 4; ++j)
      acc[i][j] = (floatx4)0.0f;

  auto stage = [&](int cur, int kt) {
    const char* ga = Apre + (size_t)kt * 8192 + tid * 16;
    gll16(ga, sm + cur * 8192 + wid * 1024);
    const char* gb = W1pre + (size_t)kt * 16384 + tid * 16;
    gll16(gb,        sm + 16384 + cur * 16384 + wid * 1024);
    gll16(gb + 8192, sm + 16384 + cur * 16384 + 8192 + wid * 1024);
  };

  auto compute = [&](int cur) {
    short8 af[4], bfr[4];
    #pragma unroll
    for (int mi = 0; mi < 4; ++mi)
      af[mi] = *(const short8*)(sm + cur * 8192 + ((wm * 4 + mi) * 64 + lane) * 16);
    #pragma unroll
    for (int ni = 0; ni < 4; ++ni)
      bfr[ni] = *(const short8*)(sm + 16384 + cur * 16384 + ((wn * 4 + ni) * 64 + lane) * 16);
    #pragma unroll
    for (int mi = 0; mi < 4; ++mi)
      #pragma unroll
      for (int ni = 0; ni < 4; ++ni)
        acc[mi][ni] = __builtin_amdgcn_mfma_f32_16x16x32_bf16(af[mi], bfr[ni], acc[mi][ni], 0, 0, 0);
  };

  // ---- Layer 1: K = 1024, BK = 32, double-buffered, async staging ----
  stage(0, 0);
  __syncthreads();
  int cur = 0;
  for (int t = 0; t < 32; ++t) {
    if (t + 1 < 32) stage(cur ^ 1, t + 1);
    compute(cur);
    __syncthreads();   // drains vmcnt(0): next buffer staged; cur safe to overwrite
    cur ^= 1;
  }

  // ---- Phase 2: layer 2 (K = 256 in 4 chunks of 64) ----
  floatx4 acc2[4][2];
  #pragma unroll
  for (int mi = 0; mi < 4; ++mi)
    #pragma unroll
    for (int qi = 0; qi < 2; ++qi)
      acc2[mi][qi] = (floatx4)0.0f;

  float b1v[4];
  #pragma unroll
  for (int ni = 0; ni < 4; ++ni)
    b1v[ni] = b1p[wn * 64 + ni * 16 + (lane & 15)];

  for (int kc = 0; kc < 4; ++kc) {
    // stage W2 chunk (16KB) async
    const char* gw = W2pre + (size_t)kc * 16384 + tid * 16;
    gll16(gw,        sm + 16384 + wid * 1024);
    gll16(gw + 8192, sm + 16384 + 8192 + wid * 1024);
    // owner waves (wn == kc) scatter relu(h1 + b1) into A-frag layout bufH
    if (wn == kc) {
      #pragma unroll
      for (int mi = 0; mi < 4; ++mi) {
        #pragma unroll
        for (int ni = 0; ni < 4; ++ni) {
          const int kl = ni * 16 + (lane & 15);            // 0..63 within chunk
          const int base = (((wm * 4 + mi) * 2 + (kl >> 5)) * 64 + ((kl >> 3) & 3) * 16) * 16
                           + (kl & 7) * 2;
          #pragma unroll
          for (int r = 0; r < 4; ++r) {
            float v = fmaxf(acc[mi][ni][r] + b1v[ni], 0.0f);
            const int row = (lane >> 4) * 4 + r;           // m & 15
            *(short*)(sm + base + row * 16) = bfbits(v);
          }
        }
      }
    }
    __syncthreads();
    #pragma unroll
    for (int ks = 0; ks < 2; ++ks) {
      short8 hf[4], wf[2];
      #pragma unroll
      for (int mi = 0; mi < 4; ++mi)
        hf[mi] = *(const short8*)(sm + (((wm * 4 + mi) * 2 + ks) * 64 + lane) * 16);
      #pragma unroll
      for (int qi = 0; qi < 2; ++qi)
        wf[qi] = *(const short8*)(sm + 16384 + (((wn * 2 + qi) * 2 + ks) * 64 + lane) * 16);
      #pragma unroll
      for (int mi = 0; mi < 4; ++mi)
        #pragma unroll
        for (int qi = 0; qi < 2; ++qi)
          acc2[mi][qi] = __builtin_amdgcn_mfma_f32_16x16x32_bf16(hf[mi], wf[qi], acc2[mi][qi], 0, 0, 0);
    }
    __syncthreads();
  }

  // ---- Layer 3: logits = relu(h2+b2) . W3 + b3 ; sigmoid; transposed store ----
  float lsum[4][4];
  #pragma unroll
  for (int mi = 0; mi < 4; ++mi)
    #pragma unroll
    for (int r = 0; r < 4; ++r) lsum[mi][r] = 0.0f;

  #pragma unroll
  for (int qi = 0; qi < 2; ++qi) {
    const int q = wn * 32 + qi * 16 + (lane & 15);
    const float b2v = b2p[q];
    const float w3v = W3p[q];
    #pragma unroll
    for (int mi = 0; mi < 4; ++mi)
      #pragma unroll
      for (int r = 0; r < 4; ++r) {
        const float h = fmaxf(acc2[mi][qi][r] + b2v, 0.0f);
        lsum[mi][r] += h * w3v;
      }
  }
  #pragma unroll
  for (int mask = 1; mask <= 8; mask <<= 1)
    #pragma unroll
    for (int mi = 0; mi < 4; ++mi)
      #pragma unroll
      for (int r = 0; r < 4; ++r)
        lsum[mi][r] += __shfl_xor(lsum[mi][r], mask, 64);

  float* part = (float*)(sm + 32768);
  if ((lane & 15) == 0) {
    const int g = lane >> 4;
    #pragma unroll
    for (int mi = 0; mi < 4; ++mi)
      #pragma unroll
      for (int r = 0; r < 4; ++r)
        part[wn * 128 + wm * 64 + mi * 16 + g * 4 + r] = lsum[mi][r];
  }
  __syncthreads();
  if (tid < 128) {
    const float x = part[tid] + part[128 + tid] + part[256 + tid] + part[384 + tid] + b3[p];
    const float s = 1.0f / (1.0f + __expf(-x));
    out[(size_t)(m0 + tid) * P_SZ + p] = s;
  }
}

// ---------------- fallback (R0 kernel, f32 reg-staged) — used when ws too small ----------------
__global__ __launch_bounds__(512, 2)
void fused_mlp_kernel(const float* __restrict__ feat,
                      const float* __restrict__ W1,
                      const float* __restrict__ b1,
                      const float* __restrict__ W2,
                      const float* __restrict__ b2,
                      const float* __restrict__ W3,
                      const float* __restrict__ b3,
                      float* __restrict__ out) {
  __shared__ __align__(16) char sm[49152];
  const int tid  = threadIdx.x;
  const int lane = tid & 63;
  const int wid  = tid >> 6;
  const int wm   = wid >> 2;
  const int wn   = wid & 3;
  const int bid = blockIdx.x;
  const int wg  = (bid & 7) * 256 + (bid >> 3);
  const int p   = wg >> 5;
  const int mt  = wg & 31;
  const int m0  = mt * 128;

  const float* featm = feat + (size_t)m0 * F_SZ;
  const float* W1p   = W1 + (size_t)p * F_SZ * H1D;
  const float* b1p   = b1 + p * H1D;
  const float* W2p   = W2 + (size_t)p * H1D * H2D;
  const float* b2p   = b2 + p * H2D;
  const float* W3p   = W3 + p * H2D;

  const int a_m  = tid >> 2;
  const int a_kg = tid & 3;
  const int b_n2 = tid & 127;
  const int b_kq = tid >> 7;

  float a_reg[8];
  float b_reg[16];
  floatx4 acc[4][4];
  #pragma unroll
  for (int i = 0; i < 4; ++i)
    #pragma unroll
    for (int j = 0; j < 4; ++j)
      acc[i][j] = (floatx4)0.0f;

  auto stage_load = [&](int k0) {
    const float* pa = featm + a_m * F_SZ + k0 + a_kg * 8;
    *(float4v*)(&a_reg[0]) = *(const float4v*)(pa);
    *(float4v*)(&a_reg[4]) = *(const float4v*)(pa + 4);
    #pragma unroll
    for (int i = 0; i < 8; ++i) {
      const float* pb = W1p + (size_t)(k0 + b_kq * 8 + i) * H1D + b_n2 * 2;
      *(float2v*)(&b_reg[2 * i]) = *(const float2v*)(pb);
    }
  };
  auto stage_write = [&](int cur) {
    short8 av;
    #pragma unroll
    for (int i = 0; i < 8; ++i) av[i] = bfbits(a_reg[i]);
    const int aslot = (a_m >> 4) * 64 + (a_m & 15) + a_kg * 16;
    *(short8*)(sm + cur * 8192 + aslot * 16) = av;
    #pragma unroll
    for (int dn = 0; dn < 2; ++dn) {
      short8 bv;
      #pragma unroll
      for (int i = 0; i < 8; ++i) bv[i] = bfbits(b_reg[2 * i + dn]);
      const int n = b_n2 * 2 + dn;
      const int bslot = (n >> 4) * 64 + (n & 15) + b_kq * 16;
      *(short8*)(sm + 16384 + cur * 16384 + bslot * 16) = bv;
    }
  };
  auto compute = [&](int cur) {
    short8 af[4], bfr[4];
    #pragma unroll
    for (int mi = 0; mi < 4; ++mi)
      af[mi] = *(const short8*)(sm + cur * 8192 + ((wm * 4 + mi) * 64 + lane) * 16);
    #pragma unroll
    for (int ni = 0; ni < 4; ++ni)
      bfr[ni] = *(const short8*)(sm + 16384 + cur * 16384 + ((wn * 4 + ni) * 64 + lane) * 16);
    #pragma unroll
    for (int mi = 0; mi < 4; ++mi)
      #pragma unroll
      for (int ni = 0; ni < 4; ++ni)
        acc[mi][ni] = __builtin_amdgcn_mfma_f32_16x16x32_bf16(af[mi], bfr[ni], acc[mi][ni], 0, 0, 0);
  };

  stage_load(0);
  stage_write(0);
  __syncthreads();
  int cur = 0;
  for (int t = 0; t < 32; ++t) {
    if (t + 1 < 32) stage_load((t + 1) * 32);
    compute(cur);
    if (t + 1 < 32) stage_write(cur ^ 1);
    __syncthreads();
    cur ^= 1;
  }

  floatx4 acc2[4][2];
  #pragma unroll
  for (int mi = 0; mi < 4; ++mi)
    #pragma unroll
    for (int qi = 0; qi < 2; ++qi)
      acc2[mi][qi] = (floatx4)0.0f;

  float b1v[4];
  #pragma unroll
  for (int ni = 0; ni < 4; ++ni)
    b1v[ni] = b1p[wn * 64 + ni * 16 + (lane & 15)];

  const int w2_q2 = tid & 63;
  const int w2_kq = tid >> 6;

  for (int kc = 0; kc < 4; ++kc) {
    const int kbase = kc * 64;
    float w2reg[16];
    #pragma unroll
    for (int i = 0; i < 8; ++i) {
      const float* pw = W2p + (size_t)(kbase + w2_kq * 8 + i) * H2D + w2_q2 * 2;
      *(float2v*)(&w2reg[2 * i]) = *(const float2v*)(pw);
    }
    #pragma unroll
    for (int dq = 0; dq < 2; ++dq) {
      short8 wv;
      #pragma unroll
      for (int i = 0; i < 8; ++i) wv[i] = bfbits(w2reg[2 * i + dq]);
      const int q = w2_q2 * 2 + dq;
      const int slot = ((q >> 4) * 2 + (w2_kq >> 2)) * 64 + (w2_kq & 3) * 16 + (q & 15);
      *(short8*)(sm + 16384 + slot * 16) = wv;
    }
    if (wn == kc) {
      #pragma unroll
      for (int mi = 0; mi < 4; ++mi) {
        #pragma unroll
        for (int ni = 0; ni < 4; ++ni) {
          const int kl = ni * 16 + (lane & 15);
          const int base = (((wm * 4 + mi) * 2 + (kl >> 5)) * 64 + ((kl >> 3) & 3) * 16) * 16
                           + (kl & 7) * 2;
          #pragma unroll
          for (int r = 0; r < 4; ++r) {
            float v = fmaxf(acc[mi][ni][r] + b1v[ni], 0.0f);
            const int row = (lane >> 4) * 4 + r;
            *(short*)(sm + base + row * 16) = bfbits(v);
          }
        }
      }
    }
    __syncthreads();
    #pragma unroll
    for (int ks = 0; ks < 2; ++ks) {
      short8 hf[4], wf[2];
      #pragma unroll
      for (int mi = 0; mi < 4; ++mi)
        hf[mi] = *(const short8*)(sm + (((wm * 4 + mi) * 2 + ks) * 64 + lane) * 16);
      #pragma unroll
      for (int qi = 0; qi < 2; ++qi)
        wf[qi] = *(const short8*)(sm + 16384 + (((wn * 2 + qi) * 2 + ks) * 64 + lane) * 16);
      #pragma unroll
      for (int mi = 0; mi < 4; ++mi)
        #pragma unroll
        for (int qi = 0; qi < 2; ++qi)
          acc2[mi][qi] = __builtin_amdgcn_mfma_f32_16x16x32_bf16(hf[mi], wf[qi], acc2[mi][qi], 0, 0, 0);
    }
    __syncthreads();
  }

  float lsum[4][4];
  #pragma unroll
  for (int mi = 0; mi < 4; ++mi)
    #pragma unroll
    for (int r = 0; r < 4; ++r) lsum[mi][r] = 0.0f;

  #pragma unroll
  for (int qi = 0; qi < 2; ++qi) {
    const int q = wn * 32 + qi * 16 + (lane & 15);
    const float b2v = b2p[q];
    const float w3v = W3p[q];
    #pragma unroll
    for (int mi = 0; mi < 4; ++mi)
      #pragma unroll
      for (int r = 0; r < 4; ++r) {
        const float h = fmaxf(acc2[mi][qi][r] + b2v, 0.0f);
        lsum[mi][r] += h * w3v;
      }
  }
  #pragma unroll
  for (int mask = 1; mask <= 8; mask <<= 1)
    #pragma unroll
    for (int mi = 0; mi < 4; ++mi)
      #pragma unroll
      for (int r = 0; r < 4; ++r)
        lsum[mi][r] += __shfl_xor(lsum[mi][r], mask, 64);

  float* part = (float*)(sm + 32768);
  if ((lane & 15) == 0) {
    const int g = lane >> 4;
    #pragma unroll
    for (int mi = 0; mi < 4; ++mi)
      #pragma unroll
      for (int r = 0; r < 4; ++r)
        part[wn * 128 + wm * 64 + mi * 16 + g * 4 + r] = lsum[mi][r];
  }
  __syncthreads();
  if (tid < 128) {
    const float x = part[tid] + part[128 + tid] + part[256 + tid] + part[384 + tid] + b3[p];
    const float s = 1.0f / (1.0f + __expf(-x));
    out[(size_t)(m0 + tid) * P_SZ + p] = s;
  }
}

extern "C" void kernel_launch(void* const* d_in, const int* in_sizes, int n_in,
                              void* d_out, int out_size, void* d_ws, size_t ws_size,
                              hipStream_t stream) {
  (void)in_sizes; (void)n_in; (void)out_size;
  const float* feat = (const float*)d_in[0];
  const float* W1   = (const float*)d_in[1];
  const float* b1   = (const float*)d_in[2];
  const float* W2   = (const float*)d_in[3];
  const float* b2   = (const float*)d_in[4];
  const float* W3   = (const float*)d_in[5];
  const float* b3   = (const float*)d_in[6];
  float* out = (float*)d_out;

  if (ws_size >= WS_NEEDED) {
    char* ws = (char*)d_ws;
    hipLaunchKernelGGL(prep_A,  dim3(2048), dim3(256), 0, stream, feat, (short8*)(ws + WS_A_OFF));
    hipLaunchKernelGGL(prep_W1, dim3(8192), dim3(256), 0, stream, W1,   (short8*)(ws + WS_W1_OFF));
    hipLaunchKernelGGL(prep_W2, dim3(1024), dim3(256), 0, stream, W2,   (short8*)(ws + WS_W2_OFF));
    hipLaunchKernelGGL(fused_mlp_v2, dim3(2048), dim3(512), 0, stream,
                       (const char*)ws, b1, b2, W3, b3, out);
  } else {
    hipLaunchKernelGGL(fused_mlp_kernel, dim3(2048), dim3(512), 0, stream,
                       feat, W1, b1, W2, b2, W3, b3, out);
  }
}

// Round 3
// 187.667 us; speedup vs baseline: 2.2592x; 1.3141x over previous
//
#include <hip/hip_runtime.h>
#include <hip/hip_bf16.h>

// Problem dims (fixed by reference)
#define B_SZ 4096
#define F_SZ 1024
#define P_SZ 64
#define H1D  256
#define H2D  128

typedef __attribute__((ext_vector_type(8))) short  short8;   // 8 bf16 (4 VGPR) MFMA operand
typedef __attribute__((ext_vector_type(4))) float  floatx4;  // MFMA accumulator
typedef __attribute__((ext_vector_type(2))) float  float2v;
typedef __attribute__((ext_vector_type(4))) float  float4v;

typedef __attribute__((address_space(1))) const void* gas_t;
typedef __attribute__((address_space(3))) void*       las_t;

__device__ __forceinline__ short bfbits(float f) {
  __bf16 h = (__bf16)f;            // RNE, v_cvt_pk_bf16_f32
  return __builtin_bit_cast(short, h);
}

__device__ __forceinline__ void gll16(const void* g, void* l) {
  __builtin_amdgcn_global_load_lds((gas_t)g, (las_t)l, 16, 0, 0);
}

// ---------------- ws layout (bf16, fragment-major) ----------------
// A_pre  [0,        8388608): feat  -> [mt(32)][kt(32)][slot(512)][8]
//        slot = f*64 + kg*16 + row ; value = feat[mt*128+f*16+row][kt*32+kg*8+j]
// W1_pre [8388608, 41943040): W1    -> [p(64)][kt(32)][slot(1024)][8]
//        slot = nf*64 + kg*16 + nr ; value = W1[p][kt*32+kg*8+j][nf*16+nr]
// W2_pre [41943040,46137344): W2    -> [p(64)][kc(4)][slot(1024)][8]
//        slot = qf*128 + ks*64 + kgl*16 + qr ; value = W2[p][kc*64+ks*32+kgl*8+j][qf*16+qr]
#define WS_A_OFF   0
#define WS_W1_OFF  8388608UL
#define WS_W2_OFF  41943040UL
#define WS_NEEDED  46137344UL

__global__ __launch_bounds__(256) void prep_A(const float* __restrict__ feat,
                                              short8* __restrict__ outv) {
  const int c = blockIdx.x * 256 + threadIdx.x;   // 524288 chunks
  const int row = c & 15, kg = (c >> 4) & 3, f = (c >> 6) & 7, kt = (c >> 9) & 31, mt = c >> 14;
  const float* src = feat + (size_t)(mt * 128 + f * 16 + row) * F_SZ + kt * 32 + kg * 8;
  float4v v0 = *(const float4v*)src;
  float4v v1 = *(const float4v*)(src + 4);
  short8 o;
  #pragma unroll
  for (int j = 0; j < 4; ++j) { o[j] = bfbits(v0[j]); o[4 + j] = bfbits(v1[j]); }
  outv[c] = o;
}

__global__ __launch_bounds__(256) void prep_W1(const float* __restrict__ W1,
                                               short8* __restrict__ outv) {
  const int c = blockIdx.x * 256 + threadIdx.x;   // 2097152 chunks
  const int nr = c & 15, kg = (c >> 4) & 3, nf = (c >> 6) & 15, kt = (c >> 10) & 31, p = c >> 15;
  const float* src = W1 + ((size_t)p * F_SZ + kt * 32 + kg * 8) * H1D + nf * 16 + nr;
  short8 o;
  #pragma unroll
  for (int j = 0; j < 8; ++j) o[j] = bfbits(src[(size_t)j * H1D]);
  outv[c] = o;
}

__global__ __launch_bounds__(256) void prep_W2(const float* __restrict__ W2,
                                               short8* __restrict__ outv) {
  const int c = blockIdx.x * 256 + threadIdx.x;   // 262144 chunks
  const int qr = c & 15, kgl = (c >> 4) & 3, ks = (c >> 6) & 1, qf = (c >> 7) & 7,
            kc = (c >> 10) & 3, p = c >> 12;
  const float* src = W2 + ((size_t)p * H1D + kc * 64 + ks * 32 + kgl * 8) * H2D + qf * 16 + qr;
  short8 o;
  #pragma unroll
  for (int j = 0; j < 8; ++j) o[j] = bfbits(src[(size_t)j * H2D]);
  outv[c] = o;
}

// ---------------- main fused kernel (triple-buffered counted-vmcnt pipeline) ----------------
// Block: one (p, 128-row m-tile). 512 threads = 8 waves (2 M x 4 N), wave tile 64x64.
// LDS: A buf i at [i*8192, +8192), i=0..2 ; B buf i at [24576 + i*16384, +16384)  -> 72KB
// Phase 2 overlay: bufH [0,16384) ; bufW2 [16384,32768) ; partial f32 [32768,34816)
__global__ __launch_bounds__(512, 2)
void fused_mlp_v3(const char* __restrict__ ws,
                  const float* __restrict__ b1,
                  const float* __restrict__ b2,
                  const float* __restrict__ W3,
                  const float* __restrict__ b3,
                  float* __restrict__ out) {
  __shared__ __align__(16) char sm[73728];

  const int tid  = threadIdx.x;
  const int lane = tid & 63;
  const int wid  = tid >> 6;
  const int wm   = wid >> 2;   // 0..1
  const int wn   = wid & 3;    // 0..3

  const int bid = blockIdx.x;
  const int wg  = (bid & 7) * 256 + (bid >> 3);   // XCD-chunked, bijective (2048%8==0)
  const int p   = wg >> 5;
  const int mt  = wg & 31;
  const int m0  = mt * 128;

  const char* Apre  = ws + WS_A_OFF  + (size_t)mt * 32 * 512 * 16;   // per-kt chunks of 8KB
  const char* W1pre = ws + WS_W1_OFF + (size_t)p  * 32 * 1024 * 16;  // per-kt chunks of 16KB
  const char* W2pre = ws + WS_W2_OFF + (size_t)p  *  4 * 1024 * 16;  // per-kc chunks of 16KB
  const float* b1p  = b1 + p * H1D;
  const float* b2p  = b2 + p * H2D;
  const float* W3p  = W3 + p * H2D;

  // Load b1 fragments BEFORE the pipelined loop so no stray VMEM ops pollute
  // the wave's vmcnt accounting inside the loop.
  float b1v[4];
  #pragma unroll
  for (int ni = 0; ni < 4; ++ni)
    b1v[ni] = b1p[wn * 64 + ni * 16 + (lane & 15)];

  floatx4 acc[4][4];
  #pragma unroll
  for (int i = 0; i < 4; ++i)
    #pragma unroll
    for (int j = 0; j < 4; ++j)
      acc[i][j] = (floatx4)0.0f;

  auto stage = [&](int ib, int kt) {   // 3 x global_load_lds (16B/lane)
    const char* ga = Apre + (size_t)kt * 8192 + tid * 16;
    gll16(ga, sm + ib * 8192 + wid * 1024);
    const char* gb = W1pre + (size_t)kt * 16384 + tid * 16;
    gll16(gb,        sm + 24576 + ib * 16384 + wid * 1024);
    gll16(gb + 8192, sm + 24576 + ib * 16384 + 8192 + wid * 1024);
  };

  // ---- Layer 1: K = 1024, BK = 32, 3-deep LDS rotation, counted vmcnt ----
  stage(0, 0);
  stage(1, 1);
  asm volatile("s_waitcnt vmcnt(3)" ::: "memory");   // buf0's 3 loads landed (b1v drained too)
  __builtin_amdgcn_s_barrier();                      // all waves: buf0 ready

  int ibr = 0;                                       // read-buffer index = t % 3
  for (int t = 0; t < 32; ++t) {
    // LDS -> VGPR fragments for tile t (compiler inserts lgkmcnt before MFMA use)
    short8 af[4], bfr[4];
    #pragma unroll
    for (int mi = 0; mi < 4; ++mi)
      af[mi] = *(const short8*)(sm + ibr * 8192 + ((wm * 4 + mi) * 64 + lane) * 16);
    #pragma unroll
    for (int ni = 0; ni < 4; ++ni)
      bfr[ni] = *(const short8*)(sm + 24576 + ibr * 16384 + ((wn * 4 + ni) * 64 + lane) * 16);

    // Prefetch tile t+2 into buffer (t+2)%3 — that buffer was read at t-1,
    // and the barrier at end of t-1 proved all waves finished reading it.
    const int ibs = (ibr == 0) ? 2 : ibr - 1;
    if (t + 2 < 32) stage(ibs, t + 2);

    __builtin_amdgcn_s_setprio(1);
    #pragma unroll
    for (int mi = 0; mi < 4; ++mi)
      #pragma unroll
      for (int ni = 0; ni < 4; ++ni)
        acc[mi][ni] = __builtin_amdgcn_mfma_f32_16x16x32_bf16(af[mi], bfr[ni], acc[mi][ni], 0, 0, 0);
    __builtin_amdgcn_s_setprio(0);

    if (t + 1 < 32) {
      if (t + 2 < 32) {
        asm volatile("s_waitcnt vmcnt(3)" ::: "memory");  // tile t+1 landed; t+2 still flying
      } else {
        asm volatile("s_waitcnt vmcnt(0)" ::: "memory");  // tail: drain last tile
      }
      __builtin_amdgcn_s_barrier();
    }
    ibr = (ibr == 2) ? 0 : ibr + 1;
  }
  __syncthreads();   // protect phase-2 overlay of buffers read at t=31

  // ---- Phase 2: layer 2 (K = 256 in 4 chunks of 64) ----
  floatx4 acc2[4][2];
  #pragma unroll
  for (int mi = 0; mi < 4; ++mi)
    #pragma unroll
    for (int qi = 0; qi < 2; ++qi)
      acc2[mi][qi] = (floatx4)0.0f;

  for (int kc = 0; kc < 4; ++kc) {
    // stage W2 chunk (16KB) async
    const char* gw = W2pre + (size_t)kc * 16384 + tid * 16;
    gll16(gw,        sm + 16384 + wid * 1024);
    gll16(gw + 8192, sm + 16384 + 8192 + wid * 1024);
    // owner waves (wn == kc) scatter relu(h1 + b1) into A-frag layout bufH
    if (wn == kc) {
      #pragma unroll
      for (int mi = 0; mi < 4; ++mi) {
        #pragma unroll
        for (int ni = 0; ni < 4; ++ni) {
          const int kl = ni * 16 + (lane & 15);            // 0..63 within chunk
          const int base = (((wm * 4 + mi) * 2 + (kl >> 5)) * 64 + ((kl >> 3) & 3) * 16) * 16
                           + (kl & 7) * 2;
          #pragma unroll
          for (int r = 0; r < 4; ++r) {
            float v = fmaxf(acc[mi][ni][r] + b1v[ni], 0.0f);
            const int row = (lane >> 4) * 4 + r;           // m & 15
            *(short*)(sm + base + row * 16) = bfbits(v);
          }
        }
      }
    }
    __syncthreads();
    #pragma unroll
    for (int ks = 0; ks < 2; ++ks) {
      short8 hf[4], wf[2];
      #pragma unroll
      for (int mi = 0; mi < 4; ++mi)
        hf[mi] = *(const short8*)(sm + (((wm * 4 + mi) * 2 + ks) * 64 + lane) * 16);
      #pragma unroll
      for (int qi = 0; qi < 2; ++qi)
        wf[qi] = *(const short8*)(sm + 16384 + (((wn * 2 + qi) * 2 + ks) * 64 + lane) * 16);
      #pragma unroll
      for (int mi = 0; mi < 4; ++mi)
        #pragma unroll
        for (int qi = 0; qi < 2; ++qi)
          acc2[mi][qi] = __builtin_amdgcn_mfma_f32_16x16x32_bf16(hf[mi], wf[qi], acc2[mi][qi], 0, 0, 0);
    }
    __syncthreads();
  }

  // ---- Layer 3: logits = relu(h2+b2) . W3 + b3 ; sigmoid; transposed store ----
  float lsum[4][4];
  #pragma unroll
  for (int mi = 0; mi < 4; ++mi)
    #pragma unroll
    for (int r = 0; r < 4; ++r) lsum[mi][r] = 0.0f;

  #pragma unroll
  for (int qi = 0; qi < 2; ++qi) {
    const int q = wn * 32 + qi * 16 + (lane & 15);
    const float b2v = b2p[q];
    const float w3v = W3p[q];
    #pragma unroll
    for (int mi = 0; mi < 4; ++mi)
      #pragma unroll
      for (int r = 0; r < 4; ++r) {
        const float h = fmaxf(acc2[mi][qi][r] + b2v, 0.0f);
        lsum[mi][r] += h * w3v;
      }
  }
  #pragma unroll
  for (int mask = 1; mask <= 8; mask <<= 1)
    #pragma unroll
    for (int mi = 0; mi < 4; ++mi)
      #pragma unroll
      for (int r = 0; r < 4; ++r)
        lsum[mi][r] += __shfl_xor(lsum[mi][r], mask, 64);

  float* part = (float*)(sm + 32768);
  if ((lane & 15) == 0) {
    const int g = lane >> 4;
    #pragma unroll
    for (int mi = 0; mi < 4; ++mi)
      #pragma unroll
      for (int r = 0; r < 4; ++r)
        part[wn * 128 + wm * 64 + mi * 16 + g * 4 + r] = lsum[mi][r];
  }
  __syncthreads();
  if (tid < 128) {
    const float x = part[tid] + part[128 + tid] + part[256 + tid] + part[384 + tid] + b3[p];
    const float s = 1.0f / (1.0f + __expf(-x));
    out[(size_t)(m0 + tid) * P_SZ + p] = s;
  }
}

// ---------------- fallback (R0 kernel, f32 reg-staged) — used when ws too small ----------------
__global__ __launch_bounds__(512, 2)
void fused_mlp_kernel(const float* __restrict__ feat,
                      const float* __restrict__ W1,
                      const float* __restrict__ b1,
                      const float* __restrict__ W2,
                      const float* __restrict__ b2,
                      const float* __restrict__ W3,
                      const float* __restrict__ b3,
                      float* __restrict__ out) {
  __shared__ __align__(16) char sm[49152];
  const int tid  = threadIdx.x;
  const int lane = tid & 63;
  const int wid  = tid >> 6;
  const int wm   = wid >> 2;
  const int wn   = wid & 3;
  const int bid = blockIdx.x;
  const int wg  = (bid & 7) * 256 + (bid >> 3);
  const int p   = wg >> 5;
  const int mt  = wg & 31;
  const int m0  = mt * 128;

  const float* featm = feat + (size_t)m0 * F_SZ;
  const float* W1p   = W1 + (size_t)p * F_SZ * H1D;
  const float* b1p   = b1 + p * H1D;
  const float* W2p   = W2 + (size_t)p * H1D * H2D;
  const float* b2p   = b2 + p * H2D;
  const float* W3p   = W3 + p * H2D;

  const int a_m  = tid >> 2;
  const int a_kg = tid & 3;
  const int b_n2 = tid & 127;
  const int b_kq = tid >> 7;

  float a_reg[8];
  float b_reg[16];
  floatx4 acc[4][4];
  #pragma unroll
  for (int i = 0; i < 4; ++i)
    #pragma unroll
    for (int j = 0; j < 4; ++j)
      acc[i][j] = (floatx4)0.0f;

  auto stage_load = [&](int k0) {
    const float* pa = featm + a_m * F_SZ + k0 + a_kg * 8;
    *(float4v*)(&a_reg[0]) = *(const float4v*)(pa);
    *(float4v*)(&a_reg[4]) = *(const float4v*)(pa + 4);
    #pragma unroll
    for (int i = 0; i < 8; ++i) {
      const float* pb = W1p + (size_t)(k0 + b_kq * 8 + i) * H1D + b_n2 * 2;
      *(float2v*)(&b_reg[2 * i]) = *(const float2v*)(pb);
    }
  };
  auto stage_write = [&](int cur) {
    short8 av;
    #pragma unroll
    for (int i = 0; i < 8; ++i) av[i] = bfbits(a_reg[i]);
    const int aslot = (a_m >> 4) * 64 + (a_m & 15) + a_kg * 16;
    *(short8*)(sm + cur * 8192 + aslot * 16) = av;
    #pragma unroll
    for (int dn = 0; dn < 2; ++dn) {
      short8 bv;
      #pragma unroll
      for (int i = 0; i < 8; ++i) bv[i] = bfbits(b_reg[2 * i + dn]);
      const int n = b_n2 * 2 + dn;
      const int bslot = (n >> 4) * 64 + (n & 15) + b_kq * 16;
      *(short8*)(sm + 16384 + cur * 16384 + bslot * 16) = bv;
    }
  };
  auto compute = [&](int cur) {
    short8 af[4], bfr[4];
    #pragma unroll
    for (int mi = 0; mi < 4; ++mi)
      af[mi] = *(const short8*)(sm + cur * 8192 + ((wm * 4 + mi) * 64 + lane) * 16);
    #pragma unroll
    for (int ni = 0; ni < 4; ++ni)
      bfr[ni] = *(const short8*)(sm + 16384 + cur * 16384 + ((wn * 4 + ni) * 64 + lane) * 16);
    #pragma unroll
    for (int mi = 0; mi < 4; ++mi)
      #pragma unroll
      for (int ni = 0; ni < 4; ++ni)
        acc[mi][ni] = __builtin_amdgcn_mfma_f32_16x16x32_bf16(af[mi], bfr[ni], acc[mi][ni], 0, 0, 0);
  };

  stage_load(0);
  stage_write(0);
  __syncthreads();
  int cur = 0;
  for (int t = 0; t < 32; ++t) {
    if (t + 1 < 32) stage_load((t + 1) * 32);
    compute(cur);
    if (t + 1 < 32) stage_write(cur ^ 1);
    __syncthreads();
    cur ^= 1;
  }

  floatx4 acc2[4][2];
  #pragma unroll
  for (int mi = 0; mi < 4; ++mi)
    #pragma unroll
    for (int qi = 0; qi < 2; ++qi)
      acc2[mi][qi] = (floatx4)0.0f;

  float b1v[4];
  #pragma unroll
  for (int ni = 0; ni < 4; ++ni)
    b1v[ni] = b1p[wn * 64 + ni * 16 + (lane & 15)];

  const int w2_q2 = tid & 63;
  const int w2_kq = tid >> 6;

  for (int kc = 0; kc < 4; ++kc) {
    const int kbase = kc * 64;
    float w2reg[16];
    #pragma unroll
    for (int i = 0; i < 8; ++i) {
      const float* pw = W2p + (size_t)(kbase + w2_kq * 8 + i) * H2D + w2_q2 * 2;
      *(float2v*)(&w2reg[2 * i]) = *(const float2v*)(pw);
    }
    #pragma unroll
    for (int dq = 0; dq < 2; ++dq) {
      short8 wv;
      #pragma unroll
      for (int i = 0; i < 8; ++i) wv[i] = bfbits(w2reg[2 * i + dq]);
      const int q = w2_q2 * 2 + dq;
      const int slot = ((q >> 4) * 2 + (w2_kq >> 2)) * 64 + (w2_kq & 3) * 16 + (q & 15);
      *(short8*)(sm + 16384 + slot * 16) = wv;
    }
    if (wn == kc) {
      #pragma unroll
      for (int mi = 0; mi < 4; ++mi) {
        #pragma unroll
        for (int ni = 0; ni < 4; ++ni) {
          const int kl = ni * 16 + (lane & 15);
          const int base = (((wm * 4 + mi) * 2 + (kl >> 5)) * 64 + ((kl >> 3) & 3) * 16) * 16
                           + (kl & 7) * 2;
          #pragma unroll
          for (int r = 0; r < 4; ++r) {
            float v = fmaxf(acc[mi][ni][r] + b1v[ni], 0.0f);
            const int row = (lane >> 4) * 4 + r;
            *(short*)(sm + base + row * 16) = bfbits(v);
          }
        }
      }
    }
    __syncthreads();
    #pragma unroll
    for (int ks = 0; ks < 2; ++ks) {
      short8 hf[4], wf[2];
      #pragma unroll
      for (int mi = 0; mi < 4; ++mi)
        hf[mi] = *(const short8*)(sm + (((wm * 4 + mi) * 2 + ks) * 64 + lane) * 16);
      #pragma unroll
      for (int qi = 0; qi < 2; ++qi)
        wf[qi] = *(const short8*)(sm + 16384 + (((wn * 2 + qi) * 2 + ks) * 64 + lane) * 16);
      #pragma unroll
      for (int mi = 0; mi < 4; ++mi)
        #pragma unroll
        for (int qi = 0; qi < 2; ++qi)
          acc2[mi][qi] = __builtin_amdgcn_mfma_f32_16x16x32_bf16(hf[mi], wf[qi], acc2[mi][qi], 0, 0, 0);
    }
    __syncthreads();
  }

  float lsum[4][4];
  #pragma unroll
  for (int mi = 0; mi < 4; ++mi)
    #pragma unroll
    for (int r = 0; r < 4; ++r) lsum[mi][r] = 0.0f;

  #pragma unroll
  for (int qi = 0; qi < 2; ++qi) {
    const int q = wn * 32 + qi * 16 + (lane & 15);
    const float b2v = b2p[q];
    const float w3v = W3p[q];
    #pragma unroll
    for (int mi = 0; mi < 4; ++mi)
      #pragma unroll
      for (int r = 0; r < 4; ++r) {
        const float h = fmaxf(acc2[mi][qi][r] + b2v, 0.0f);
        lsum[mi][r] += h * w3v;
      }
  }
  #pragma unroll
  for (int mask = 1; mask <= 8; mask <<= 1)
    #pragma unroll
    for (int mi = 0; mi < 4; ++mi)
      #pragma unroll
      for (int r = 0; r < 4; ++r)
        lsum[mi][r] += __shfl_xor(lsum[mi][r], mask, 64);

  float* part = (float*)(sm + 32768);
  if ((lane & 15) == 0) {
    const int g = lane >> 4;
    #pragma unroll
    for (int mi = 0; mi < 4; ++mi)
      #pragma unroll
      for (int r = 0; r < 4; ++r)
        part[wn * 128 + wm * 64 + mi * 16 + g * 4 + r] = lsum[mi][r];
  }
  __syncthreads();
  if (tid < 128) {
    const float x = part[tid] + part[128 + tid] + part[256 + tid] + part[384 + tid] + b3[p];
    const float s = 1.0f / (1.0f + __expf(-x));
    out[(size_t)(m0 + tid) * P_SZ + p] = s;
  }
}

extern "C" void kernel_launch(void* const* d_in, const int* in_sizes, int n_in,
                              void* d_out, int out_size, void* d_ws, size_t ws_size,
                              hipStream_t stream) {
  (void)in_sizes; (void)n_in; (void)out_size;
  const float* feat = (const float*)d_in[0];
  const float* W1   = (const float*)d_in[1];
  const float* b1   = (const float*)d_in[2];
  const float* W2   = (const float*)d_in[3];
  const float* b2   = (const float*)d_in[4];
  const float* W3   = (const float*)d_in[5];
  const float* b3   = (const float*)d_in[6];
  float* out = (float*)d_out;

  if (ws_size >= WS_NEEDED) {
    char* ws = (char*)d_ws;
    hipLaunchKernelGGL(prep_A,  dim3(2048), dim3(256), 0, stream, feat, (short8*)(ws + WS_A_OFF));
    hipLaunchKernelGGL(prep_W1, dim3(8192), dim3(256), 0, stream, W1,   (short8*)(ws + WS_W1_OFF));
    hipLaunchKernelGGL(prep_W2, dim3(1024), dim3(256), 0, stream, W2,   (short8*)(ws + WS_W2_OFF));
    hipLaunchKernelGGL(fused_mlp_v3, dim3(2048), dim3(512), 0, stream,
                       (const char*)ws, b1, b2, W3, b3, out);
  } else {
    hipLaunchKernelGGL(fused_mlp_kernel, dim3(2048), dim3(512), 0, stream,
                       feat, W1, b1, W2, b2, W3, b3, out);
  }
}

// Round 5
// 161.989 us; speedup vs baseline: 2.6173x; 1.1585x over previous
//
#include <hip/hip_runtime.h>
#include <hip/hip_bf16.h>

// Problem dims (fixed by reference)
#define B_SZ 4096
#define F_SZ 1024
#define P_SZ 64
#define H1D  256
#define H2D  128

typedef __attribute__((ext_vector_type(8))) short  short8;   // 8 bf16 (4 VGPR) MFMA operand
typedef __attribute__((ext_vector_type(4))) float  floatx4;  // MFMA accumulator
typedef __attribute__((ext_vector_type(2))) float  float2v;
typedef __attribute__((ext_vector_type(4))) float  float4v;

typedef __attribute__((address_space(1))) const void* gas_t;
typedef __attribute__((address_space(3))) void*       las_t;

__device__ __forceinline__ short bfbits(float f) {
  __bf16 h = (__bf16)f;            // RNE, v_cvt_pk_bf16_f32
  return __builtin_bit_cast(short, h);
}

__device__ __forceinline__ void gll16(const void* g, void* l) {
  __builtin_amdgcn_global_load_lds((gas_t)g, (las_t)l, 16, 0, 0);
}

// ---------------- ws layout (bf16, fragment-major) ----------------
// A_pre  [0,        8388608): feat  -> [mt128(32)][kt(32)][slot(512)][8]
//        slot = f*64 + kg*16 + row ; value = feat[mt*128+f*16+row][kt*32+kg*8+j]
// W1_pre [8388608, 41943040): W1    -> [p(64)][kt(32)][slot(1024)][8]
//        slot = nf*64 + kg*16 + nr ; value = W1[p][kt*32+kg*8+j][nf*16+nr]
// W2_pre [41943040,46137344): W2    -> [p(64)][kc(4)][slot(1024)][8]
//        slot = qf*128 + ks*64 + kgl*16 + qr ; value = W2[p][kc*64+ks*32+kgl*8+j][qf*16+qr]
#define WS_A_OFF   0
#define WS_W1_OFF  8388608UL
#define WS_W2_OFF  41943040UL
#define WS_NEEDED  46137344UL

__global__ __launch_bounds__(256) void prep_A(const float* __restrict__ feat,
                                              short8* __restrict__ outv) {
  const int c = blockIdx.x * 256 + threadIdx.x;   // 524288 chunks
  const int row = c & 15, kg = (c >> 4) & 3, f = (c >> 6) & 7, kt = (c >> 9) & 31, mt = c >> 14;
  const float* src = feat + (size_t)(mt * 128 + f * 16 + row) * F_SZ + kt * 32 + kg * 8;
  float4v v0 = *(const float4v*)src;
  float4v v1 = *(const float4v*)(src + 4);
  short8 o;
  #pragma unroll
  for (int j = 0; j < 4; ++j) { o[j] = bfbits(v0[j]); o[4 + j] = bfbits(v1[j]); }
  outv[c] = o;
}

__global__ __launch_bounds__(256) void prep_W1(const float* __restrict__ W1,
                                               short8* __restrict__ outv) {
  const int c = blockIdx.x * 256 + threadIdx.x;   // 2097152 chunks
  const int nr = c & 15, kg = (c >> 4) & 3, nf = (c >> 6) & 15, kt = (c >> 10) & 31, p = c >> 15;
  const float* src = W1 + ((size_t)p * F_SZ + kt * 32 + kg * 8) * H1D + nf * 16 + nr;
  short8 o;
  #pragma unroll
  for (int j = 0; j < 8; ++j) o[j] = bfbits(src[(size_t)j * H1D]);
  outv[c] = o;
}

__global__ __launch_bounds__(256) void prep_W2(const float* __restrict__ W2,
                                               short8* __restrict__ outv) {
  const int c = blockIdx.x * 256 + threadIdx.x;   // 262144 chunks
  const int qr = c & 15, kgl = (c >> 4) & 3, ks = (c >> 6) & 1, qf = (c >> 7) & 7,
            kc = (c >> 10) & 3, p = c >> 12;
  const float* src = W2 + ((size_t)p * H1D + kc * 64 + ks * 32 + kgl * 8) * H2D + qf * 16 + qr;
  short8 o;
  #pragma unroll
  for (int j = 0; j < 8; ++j) o[j] = bfbits(src[(size_t)j * H2D]);
  outv[c] = o;
}

// ---------------- main fused kernel: 256x256 tile, 3-deep counted-vmcnt pipeline ----------------
// Block: one (p, 256-row m-tile). 512 threads = 8 waves (2M x 4N), wave tile 128x64.
// LDS map (135168 bytes):
//   L1 bufs  [0, 98304):       3 x 32KB { A chunk0 8K | A chunk1 8K | B 16K }
//   W2       [65536, 131072):  64KB, staged at t=30/31 (buf2 dead after t=29 + virgin space)
//   bufH     overlay [0, 65536): ONE k-parity half of h1 (256m x 128k bf16), A-frag-major
//            frag = s*16 + (m>>4), s=0..3 holds q-tile kt2 = 2*s + h
//   partials [131072, 135168): f32 [wn(4)][m(256)]
__global__ __launch_bounds__(512, 2)
void fused_mlp_v5(const char* __restrict__ ws,
                  const float* __restrict__ b1,
                  const float* __restrict__ b2,
                  const float* __restrict__ W3,
                  const float* __restrict__ b3,
                  float* __restrict__ out) {
  __shared__ __align__(16) char sm[135168];

  const int tid  = threadIdx.x;
  const int lane = tid & 63;
  const int wid  = tid >> 6;
  const int wm   = wid >> 2;   // 0..1 : m-half (128 rows)
  const int wn   = wid & 3;    // 0..3 : n-quarter (64 cols of H1)

  const int bid = blockIdx.x;
  const int wg  = (bid & 7) * 128 + (bid >> 3);   // XCD-chunked, bijective (1024%8==0)
  const int p   = wg >> 4;                        // 16 m-tiles per p
  const int mt  = wg & 15;
  const int m0  = mt * 256;

  const char* Apre  = ws + WS_A_OFF  + (size_t)(2 * mt) * 262144;  // two 128-row chunks
  const char* W1pre = ws + WS_W1_OFF + (size_t)p * 524288;         // per-kt 16KB
  const char* W2pre = ws + WS_W2_OFF + (size_t)p * 65536;          // 64KB total

  floatx4 acc[8][4];
  #pragma unroll
  for (int i = 0; i < 8; ++i)
    #pragma unroll
    for (int j = 0; j < 4; ++j)
      acc[i][j] = (floatx4)0.0f;

  auto stage = [&](int ib, int kt) {   // 4 x global_load_lds (16B/lane), 32KB/tile
    char* base = sm + ib * 32768;
    gll16(Apre + (size_t)kt * 8192 + tid * 16,          base + wid * 1024);
    gll16(Apre + 262144 + (size_t)kt * 8192 + tid * 16, base + 8192 + wid * 1024);
    const char* gb = W1pre + (size_t)kt * 16384 + tid * 16;
    gll16(gb,        base + 16384 + wid * 1024);
    gll16(gb + 8192, base + 24576 + wid * 1024);
  };

  // ---- Layer 1: K = 1024, BK = 32, 3-deep rotation, counted vmcnt(4) ----
  stage(0, 0);
  stage(1, 1);
  asm volatile("s_waitcnt vmcnt(4)" ::: "memory");   // tile0 landed; tile1 in flight
  __builtin_amdgcn_s_barrier();

  int ibr = 0;
  for (int t = 0; t < 32; ++t) {
    short8 af[8], bfr[4];
    #pragma unroll
    for (int mi = 0; mi < 8; ++mi)
      af[mi] = *(const short8*)(sm + ibr * 32768 + (wm * 8 + mi) * 1024 + lane * 16);
    #pragma unroll
    for (int ni = 0; ni < 4; ++ni)
      bfr[ni] = *(const short8*)(sm + ibr * 32768 + 16384 + (wn * 4 + ni) * 1024 + lane * 16);

    // Prefetch tile t+2 into the buffer freed at t-1; in the last two steps
    // stage the 64KB W2 block instead (same 4-load slot keeps vmcnt counts).
    // W2 dest [65536,131072) overlays buf2 (dead after t=29) + virgin space.
    const int ibs = (ibr == 0) ? 2 : ibr - 1;
    if (t < 30) {
      stage(ibs, t + 2);
    } else {
      const int j0 = (t - 30) * 4;
      #pragma unroll
      for (int j = 0; j < 4; ++j)
        gll16(W2pre + (size_t)(j0 + j) * 8192 + tid * 16,
              sm + 65536 + (j0 + j) * 8192 + wid * 1024);
    }

    __builtin_amdgcn_s_setprio(1);
    #pragma unroll
    for (int mi = 0; mi < 8; ++mi)
      #pragma unroll
      for (int ni = 0; ni < 4; ++ni)
        acc[mi][ni] = __builtin_amdgcn_mfma_f32_16x16x32_bf16(af[mi], bfr[ni], acc[mi][ni], 0, 0, 0);
    __builtin_amdgcn_s_setprio(0);

    if (t < 31) {
      asm volatile("s_waitcnt vmcnt(4)" ::: "memory");  // tile t+1 landed; newest 4 still flying
      __builtin_amdgcn_s_barrier();
    }
    ibr = (ibr == 2) ? 0 : ibr + 1;
  }
  __syncthreads();   // full drain: W2 staged, all L1 LDS reads consumed -> bufs 0/1 reusable

  // ---- Phase 2: layer 2 in two k-parity halves (bufH holds one half = 64KB) ----
  float b1v[4];
  #pragma unroll
  for (int ni = 0; ni < 4; ++ni)
    b1v[ni] = b1[p * H1D + wn * 64 + ni * 16 + (lane & 15)];

  floatx4 acc2[8][2];
  #pragma unroll
  for (int mi = 0; mi < 8; ++mi)
    #pragma unroll
    for (int qi = 0; qi < 2; ++qi)
      acc2[mi][qi] = (floatx4)0.0f;

  const int c  = lane & 15;
  const int hi = lane >> 4;

  #pragma unroll
  for (int h = 0; h < 2; ++h) {
    // scatter relu(h1+b1) for q-tiles kt2 = 2*wn + h into bufH slot s = wn
    #pragma unroll
    for (int mi = 0; mi < 8; ++mi)
      #pragma unroll
      for (int ii = 0; ii < 2; ++ii) {
        const int ni  = h * 2 + ii;
        const int kg2 = ii * 2 + (c >> 3);                // k-group of 8 within 32-k tile
        const int base = (wn * 16 + wm * 8 + mi) * 1024 + kg2 * 256 + (c & 7) * 2;
        #pragma unroll
        for (int r = 0; r < 4; ++r) {
          const float v = fmaxf(acc[mi][ni][r] + b1v[ni], 0.0f);
          *(short*)(sm + base + (hi * 4 + r) * 16) = bfbits(v);
        }
      }
    __syncthreads();   // scatter visible (and W2/b1 drained on h=0)

    // compute: slot s holds q-tile kt2 = 2s+h ; W2 chunk kc=s, ks=h
    #pragma unroll
    for (int s = 0; s < 4; ++s) {
      short8 hf[8], wf[2];
      #pragma unroll
      for (int mi = 0; mi < 8; ++mi)
        hf[mi] = *(const short8*)(sm + (s * 16 + wm * 8 + mi) * 1024 + lane * 16);
      #pragma unroll
      for (int qi = 0; qi < 2; ++qi)
        wf[qi] = *(const short8*)(sm + 65536 + s * 16384 + (wn * 2 + qi) * 2048
                                  + h * 1024 + lane * 16);
      #pragma unroll
      for (int mi = 0; mi < 8; ++mi)
        #pragma unroll
        for (int qi = 0; qi < 2; ++qi)
          acc2[mi][qi] = __builtin_amdgcn_mfma_f32_16x16x32_bf16(hf[mi], wf[qi], acc2[mi][qi], 0, 0, 0);
    }
    __syncthreads();   // all reads of bufH done before next half's scatter
  }

  // ---- Layer 3: logits = relu(h2+b2) . W3 + b3 ; sigmoid; transposed store ----
  float lsum[8][4];
  #pragma unroll
  for (int mi = 0; mi < 8; ++mi)
    #pragma unroll
    for (int r = 0; r < 4; ++r) lsum[mi][r] = 0.0f;

  #pragma unroll
  for (int qi = 0; qi < 2; ++qi) {
    const int q = wn * 32 + qi * 16 + c;
    const float b2v = b2[p * H2D + q];
    const float w3v = W3[p * H2D + q];
    #pragma unroll
    for (int mi = 0; mi < 8; ++mi)
      #pragma unroll
      for (int r = 0; r < 4; ++r) {
        const float h2v = fmaxf(acc2[mi][qi][r] + b2v, 0.0f);
        lsum[mi][r] += h2v * w3v;
      }
  }
  #pragma unroll
  for (int mask = 1; mask <= 8; mask <<= 1)
    #pragma unroll
    for (int mi = 0; mi < 8; ++mi)
      #pragma unroll
      for (int r = 0; r < 4; ++r)
        lsum[mi][r] += __shfl_xor(lsum[mi][r], mask, 64);

  float* part = (float*)(sm + 131072);   // [wn(4)][m(256)]
  if (c == 0) {
    #pragma unroll
    for (int mi = 0; mi < 8; ++mi)
      #pragma unroll
      for (int r = 0; r < 4; ++r)
        part[wn * 256 + wm * 128 + mi * 16 + hi * 4 + r] = lsum[mi][r];
  }
  __syncthreads();
  if (tid < 256) {
    const float x = part[tid] + part[256 + tid] + part[512 + tid] + part[768 + tid] + b3[p];
    const float s = 1.0f / (1.0f + __expf(-x));
    out[(size_t)(m0 + tid) * P_SZ + p] = s;
  }
}

// ---------------- fallback (R0 kernel, f32 reg-staged) — used when ws too small ----------------
__global__ __launch_bounds__(512, 2)
void fused_mlp_kernel(const float* __restrict__ feat,
                      const float* __restrict__ W1,
                      const float* __restrict__ b1,
                      const float* __restrict__ W2,
                      const float* __restrict__ b2,
                      const float* __restrict__ W3,
                      const float* __restrict__ b3,
                      float* __restrict__ out) {
  __shared__ __align__(16) char sm[49152];
  const int tid  = threadIdx.x;
  const int lane = tid & 63;
  const int wid  = tid >> 6;
  const int wm   = wid >> 2;
  const int wn   = wid & 3;
  const int bid = blockIdx.x;
  const int wg  = (bid & 7) * 256 + (bid >> 3);
  const int p   = wg >> 5;
  const int mt  = wg & 31;
  const int m0  = mt * 128;

  const float* featm = feat + (size_t)m0 * F_SZ;
  const float* W1p   = W1 + (size_t)p * F_SZ * H1D;
  const float* b1p   = b1 + p * H1D;
  const float* W2p   = W2 + (size_t)p * H1D * H2D;
  const float* b2p   = b2 + p * H2D;
  const float* W3p   = W3 + p * H2D;

  const int a_m  = tid >> 2;
  const int a_kg = tid & 3;
  const int b_n2 = tid & 127;
  const int b_kq = tid >> 7;

  float a_reg[8];
  float b_reg[16];
  floatx4 acc[4][4];
  #pragma unroll
  for (int i = 0; i < 4; ++i)
    #pragma unroll
    for (int j = 0; j < 4; ++j)
      acc[i][j] = (floatx4)0.0f;

  auto stage_load = [&](int k0) {
    const float* pa = featm + a_m * F_SZ + k0 + a_kg * 8;
    *(float4v*)(&a_reg[0]) = *(const float4v*)(pa);
    *(float4v*)(&a_reg[4]) = *(const float4v*)(pa + 4);
    #pragma unroll
    for (int i = 0; i < 8; ++i) {
      const float* pb = W1p + (size_t)(k0 + b_kq * 8 + i) * H1D + b_n2 * 2;
      *(float2v*)(&b_reg[2 * i]) = *(const float2v*)(pb);
    }
  };
  auto stage_write = [&](int cur) {
    short8 av;
    #pragma unroll
    for (int i = 0; i < 8; ++i) av[i] = bfbits(a_reg[i]);
    const int aslot = (a_m >> 4) * 64 + (a_m & 15) + a_kg * 16;
    *(short8*)(sm + cur * 8192 + aslot * 16) = av;
    #pragma unroll
    for (int dn = 0; dn < 2; ++dn) {
      short8 bv;
      #pragma unroll
      for (int i = 0; i < 8; ++i) bv[i] = bfbits(b_reg[2 * i + dn]);
      const int n = b_n2 * 2 + dn;
      const int bslot = (n >> 4) * 64 + (n & 15) + b_kq * 16;
      *(short8*)(sm + 16384 + cur * 16384 + bslot * 16) = bv;
    }
  };
  auto compute = [&](int cur) {
    short8 af[4], bfr[4];
    #pragma unroll
    for (int mi = 0; mi < 4; ++mi)
      af[mi] = *(const short8*)(sm + cur * 8192 + ((wm * 4 + mi) * 64 + lane) * 16);
    #pragma unroll
    for (int ni = 0; ni < 4; ++ni)
      bfr[ni] = *(const short8*)(sm + 16384 + cur * 16384 + ((wn * 4 + ni) * 64 + lane) * 16);
    #pragma unroll
    for (int mi = 0; mi < 4; ++mi)
      #pragma unroll
      for (int ni = 0; ni < 4; ++ni)
        acc[mi][ni] = __builtin_amdgcn_mfma_f32_16x16x32_bf16(af[mi], bfr[ni], acc[mi][ni], 0, 0, 0);
  };

  stage_load(0);
  stage_write(0);
  __syncthreads();
  int cur = 0;
  for (int t = 0; t < 32; ++t) {
    if (t + 1 < 32) stage_load((t + 1) * 32);
    compute(cur);
    if (t + 1 < 32) stage_write(cur ^ 1);
    __syncthreads();
    cur ^= 1;
  }

  floatx4 acc2[4][2];
  #pragma unroll
  for (int mi = 0; mi < 4; ++mi)
    #pragma unroll
    for (int qi = 0; qi < 2; ++qi)
      acc2[mi][qi] = (floatx4)0.0f;

  float b1v[4];
  #pragma unroll
  for (int ni = 0; ni < 4; ++ni)
    b1v[ni] = b1p[wn * 64 + ni * 16 + (lane & 15)];

  const int w2_q2 = tid & 63;
  const int w2_kq = tid >> 6;

  for (int kc = 0; kc < 4; ++kc) {
    const int kbase = kc * 64;
    float w2reg[16];
    #pragma unroll
    for (int i = 0; i < 8; ++i) {
      const float* pw = W2p + (size_t)(kbase + w2_kq * 8 + i) * H2D + w2_q2 * 2;
      *(float2v*)(&w2reg[2 * i]) = *(const float2v*)(pw);
    }
    #pragma unroll
    for (int dq = 0; dq < 2; ++dq) {
      short8 wv;
      #pragma unroll
      for (int i = 0; i < 8; ++i) wv[i] = bfbits(w2reg[2 * i + dq]);
      const int q = w2_q2 * 2 + dq;
      const int slot = ((q >> 4) * 2 + (w2_kq >> 2)) * 64 + (w2_kq & 3) * 16 + (q & 15);
      *(short8*)(sm + 16384 + slot * 16) = wv;
    }
    if (wn == kc) {
      #pragma unroll
      for (int mi = 0; mi < 4; ++mi) {
        #pragma unroll
        for (int ni = 0; ni < 4; ++ni) {
          const int kl = ni * 16 + (lane & 15);
          const int base = (((wm * 4 + mi) * 2 + (kl >> 5)) * 64 + ((kl >> 3) & 3) * 16) * 16
                           + (kl & 7) * 2;
          #pragma unroll
          for (int r = 0; r < 4; ++r) {
            float v = fmaxf(acc[mi][ni][r] + b1v[ni], 0.0f);
            const int row = (lane >> 4) * 4 + r;
            *(short*)(sm + base + row * 16) = bfbits(v);
          }
        }
      }
    }
    __syncthreads();
    #pragma unroll
    for (int ks = 0; ks < 2; ++ks) {
      short8 hf[4], wf[2];
      #pragma unroll
      for (int mi = 0; mi < 4; ++mi)
        hf[mi] = *(const short8*)(sm + (((wm * 4 + mi) * 2 + ks) * 64 + lane) * 16);
      #pragma unroll
      for (int qi = 0; qi < 2; ++qi)
        wf[qi] = *(const short8*)(sm + 16384 + (((wn * 2 + qi) * 2 + ks) * 64 + lane) * 16);
      #pragma unroll
      for (int mi = 0; mi < 4; ++mi)
        #pragma unroll
        for (int qi = 0; qi < 2; ++qi)
          acc2[mi][qi] = __builtin_amdgcn_mfma_f32_16x16x32_bf16(hf[mi], wf[qi], acc2[mi][qi], 0, 0, 0);
    }
    __syncthreads();
  }

  float lsum[4][4];
  #pragma unroll
  for (int mi = 0; mi < 4; ++mi)
    #pragma unroll
    for (int r = 0; r < 4; ++r) lsum[mi][r] = 0.0f;

  #pragma unroll
  for (int qi = 0; qi < 2; ++qi) {
    const int q = wn * 32 + qi * 16 + (lane & 15);
    const float b2v = b2p[q];
    const float w3v = W3p[q];
    #pragma unroll
    for (int mi = 0; mi < 4; ++mi)
      #pragma unroll
      for (int r = 0; r < 4; ++r) {
        const float h = fmaxf(acc2[mi][qi][r] + b2v, 0.0f);
        lsum[mi][r] += h * w3v;
      }
  }
  #pragma unroll
  for (int mask = 1; mask <= 8; mask <<= 1)
    #pragma unroll
    for (int mi = 0; mi < 4; ++mi)
      #pragma unroll
      for (int r = 0; r < 4; ++r)
        lsum[mi][r] += __shfl_xor(lsum[mi][r], mask, 64);

  float* part = (float*)(sm + 32768);
  if ((lane & 15) == 0) {
    const int g = lane >> 4;
    #pragma unroll
    for (int mi = 0; mi < 4; ++mi)
      #pragma unroll
      for (int r = 0; r < 4; ++r)
        part[wn * 128 + wm * 64 + mi * 16 + g * 4 + r] = lsum[mi][r];
  }
  __syncthreads();
  if (tid < 128) {
    const float x = part[tid] + part[128 + tid] + part[256 + tid] + part[384 + tid] + b3[p];
    const float s = 1.0f / (1.0f + __expf(-x));
    out[(size_t)(m0 + tid) * P_SZ + p] = s;
  }
}

extern "C" void kernel_launch(void* const* d_in, const int* in_sizes, int n_in,
                              void* d_out, int out_size, void* d_ws, size_t ws_size,
                              hipStream_t stream) {
  (void)in_sizes; (void)n_in; (void)out_size;
  const float* feat = (const float*)d_in[0];
  const float* W1   = (const float*)d_in[1];
  const float* b1   = (const float*)d_in[2];
  const float* W2   = (const float*)d_in[3];
  const float* b2   = (const float*)d_in[4];
  const float* W3   = (const float*)d_in[5];
  const float* b3   = (const float*)d_in[6];
  float* out = (float*)d_out;

  if (ws_size >= WS_NEEDED) {
    char* ws = (char*)d_ws;
    hipLaunchKernelGGL(prep_A,  dim3(2048), dim3(256), 0, stream, feat, (short8*)(ws + WS_A_OFF));
    hipLaunchKernelGGL(prep_W1, dim3(8192), dim3(256), 0, stream, W1,   (short8*)(ws + WS_W1_OFF));
    hipLaunchKernelGGL(prep_W2, dim3(1024), dim3(256), 0, stream, W2,   (short8*)(ws + WS_W2_OFF));
    hipLaunchKernelGGL(fused_mlp_v5, dim3(1024), dim3(512), 0, stream,
                       (const char*)ws, b1, b2, W3, b3, out);
  } else {
    hipLaunchKernelGGL(fused_mlp_kernel, dim3(2048), dim3(512), 0, stream,
                       feat, W1, b1, W2, b2, W3, b3, out);
  }
}